// Round 1
// baseline (344.044 us; speedup 1.0000x reference)
//
#include <hip/hip_runtime.h>
#include <hip/hip_bf16.h>

#define NREAL 20000
#define MPAD  20032      // 313 * 64
#define HDIM  256
#define ODIM  128
#define NEDGE 320000

typedef __attribute__((ext_vector_type(4))) float f32x4;
typedef __attribute__((ext_vector_type(8))) short s16x8;

__device__ inline unsigned short f2bf(float f) {
    unsigned int u = __float_as_uint(f);
    unsigned int r = (u + 0x7FFFu + ((u >> 16) & 1u)) >> 16;
    return (unsigned short)r;
}
__device__ inline float bf2f(unsigned short s) {
    return __uint_as_float(((unsigned int)s) << 16);
}

// ---------------- CSR build ----------------
__global__ void k_degree(const int* __restrict__ dst, int* __restrict__ deg) {
    int e = blockIdx.x * 256 + threadIdx.x;
    if (e < NEDGE) atomicAdd(&deg[dst[e]], 1);
}

__global__ __launch_bounds__(1024) void k_scan(const int* __restrict__ deg,
                                               int* __restrict__ rowptr,
                                               int* __restrict__ cursor) {
    __shared__ int sm[1024];
    __shared__ int carry;
    int t = threadIdx.x;
    if (t == 0) carry = 0;
    __syncthreads();
    for (int base = 0; base < NREAL; base += 1024) {
        int v = (base + t < NREAL) ? deg[base + t] : 0;
        sm[t] = v;
        __syncthreads();
        for (int off = 1; off < 1024; off <<= 1) {
            int x2 = (t >= off) ? sm[t - off] : 0;
            __syncthreads();
            if (t >= off) sm[t] += x2;
            __syncthreads();
        }
        int c = carry;
        int excl = sm[t] - v;
        if (base + t < NREAL) { rowptr[base + t] = c + excl; cursor[base + t] = c + excl; }
        int tot = sm[1023];
        __syncthreads();
        if (t == 0) carry = c + tot;
        __syncthreads();
    }
    if (t == 0) rowptr[NREAL] = carry;
}

__global__ void k_fill(const int* __restrict__ src, const int* __restrict__ dst,
                       const float* __restrict__ attr, int* __restrict__ cursor,
                       int* __restrict__ csr_src, float* __restrict__ csr_attr) {
    int e = blockIdx.x * 256 + threadIdx.x;
    if (e < NEDGE) {
        int d = dst[e];
        int p = atomicAdd(&cursor[d], 1);
        csr_src[p]  = src[e];
        csr_attr[p] = attr[e];
    }
}

// ---------------- pad-copy x -> hA ----------------
__global__ void k_padcopy(const float* __restrict__ x, float* __restrict__ h) {
    long gid  = (long)blockIdx.x * 256 + threadIdx.x;
    long base = gid * 4;
    if (base >= (long)MPAD * HDIM) return;
    long row = base >> 8;
    f32x4 v;
    if (row < NREAL) v = *(const f32x4*)(x + base);
    else { v[0] = 0.f; v[1] = 0.f; v[2] = 0.f; v[3] = 0.f; }
    *(f32x4*)(h + base) = v;
}

// ---------------- aggregation: agg[i] = sum_{e: dst=i} attr[e] * h[src[e]] ----------------
__global__ __launch_bounds__(256) void k_aggregate(
    const float* __restrict__ h, const int* __restrict__ rowptr,
    const int* __restrict__ csr_src, const float* __restrict__ csr_attr,
    float* __restrict__ agg)
{
    int node = blockIdx.x;
    int t = threadIdx.x;
    float acc = 0.f;
    __shared__ int   s_src[256];
    __shared__ float s_attr[256];
    if (node < NREAL) {
        int beg = rowptr[node], end = rowptr[node + 1];
        for (int chunk = beg; chunk < end; chunk += 256) {
            int m = end - chunk; if (m > 256) m = 256;
            __syncthreads();
            if (t < m) { s_src[t] = csr_src[chunk + t]; s_attr[t] = csr_attr[chunk + t]; }
            __syncthreads();
            for (int j = 0; j < m; ++j)
                acc += s_attr[j] * h[(long)s_src[j] * HDIM + t];
        }
    }
    agg[(long)node * HDIM + t] = acc;
}

// ---------------- GEMM: C = relu(A1@B1 [+ A2@B2] + bias) ----------------
// A: [MPAD, 256] f32.  B: [256, Nt] f32 row-major.  Split-A bf16 MFMA (hi+lo).
__global__ __launch_bounds__(256) void k_gemm(
    const float* __restrict__ A1, const float* __restrict__ A2,
    const float* __restrict__ B1, const float* __restrict__ B2,
    const float* __restrict__ bias, float* __restrict__ Cout,
    int Nt, int Mreal)
{
    __shared__ __align__(16) short Ahi[64][48];
    __shared__ __align__(16) short Alo[64][48];
    __shared__ __align__(16) short Bt [64][48];   // [n][k]

    const int t    = threadIdx.x;
    const int bm   = blockIdx.x, bn = blockIdx.y;
    const int lane = t & 63;
    const int wave = t >> 6;
    const int wr   = (wave >> 1) * 32;
    const int wc   = (wave & 1) * 32;
    const int lrow = lane & 15;
    const int lk   = (lane >> 4) * 8;

    f32x4 acc[2][2];
    for (int i = 0; i < 2; ++i)
        for (int j = 0; j < 2; ++j)
            for (int r = 0; r < 4; ++r) acc[i][j][r] = 0.f;

    const int  ar   = t >> 2;          // 0..63
    const int  ac   = (t & 3) * 8;     // 0,8,16,24
    const long arow = (long)bm * 64 + ar;

    const int nmat = A2 ? 2 : 1;
    for (int mat = 0; mat < nmat; ++mat) {
        const float* A = mat ? A2 : A1;
        const float* B = mat ? B2 : B1;
        for (int k0 = 0; k0 < HDIM; k0 += 32) {
            __syncthreads();
            // stage A (64x32) as hi/lo bf16
            {
                const float* ap = A + arow * HDIM + k0 + ac;
                f32x4 v0 = *(const f32x4*)ap;
                f32x4 v1 = *(const f32x4*)(ap + 4);
                float vv[8];
                for (int j = 0; j < 4; ++j) { vv[j] = v0[j]; vv[4 + j] = v1[j]; }
                s16x8 hi8, lo8;
                for (int j = 0; j < 8; ++j) {
                    unsigned short h = f2bf(vv[j]);
                    hi8[j] = (short)h;
                    lo8[j] = (short)f2bf(vv[j] - bf2f(h));
                }
                *(s16x8*)&Ahi[ar][ac] = hi8;
                *(s16x8*)&Alo[ar][ac] = lo8;
            }
            // stage B (32x64) transposed -> Bt[n][k]
            {
                int n  = t >> 2;
                int kk = (t & 3) * 8;
                const float* bp = B + (long)(k0 + kk) * Nt + bn * 64 + n;
                s16x8 b8;
                for (int j = 0; j < 8; ++j) b8[j] = (short)f2bf(bp[(long)j * Nt]);
                *(s16x8*)&Bt[n][kk] = b8;
            }
            __syncthreads();
            // MFMA: each wave does 32x32 = 2x2 tiles of 16x16x32, hi+lo
            s16x8 bfrag[2];
            bfrag[0] = *(const s16x8*)&Bt[wc + lrow     ][lk];
            bfrag[1] = *(const s16x8*)&Bt[wc + 16 + lrow][lk];
            for (int mi = 0; mi < 2; ++mi) {
                s16x8 ahi = *(const s16x8*)&Ahi[wr + mi * 16 + lrow][lk];
                s16x8 alo = *(const s16x8*)&Alo[wr + mi * 16 + lrow][lk];
                for (int nj = 0; nj < 2; ++nj) {
                    acc[mi][nj] = __builtin_amdgcn_mfma_f32_16x16x32_bf16(ahi, bfrag[nj], acc[mi][nj], 0, 0, 0);
                    acc[mi][nj] = __builtin_amdgcn_mfma_f32_16x16x32_bf16(alo, bfrag[nj], acc[mi][nj], 0, 0, 0);
                }
            }
        }
    }
    // epilogue: bias + relu, masked store
    const int rbase = (lane >> 4) * 4;
    for (int mi = 0; mi < 2; ++mi) {
        for (int nj = 0; nj < 2; ++nj) {
            int col = bn * 64 + wc + nj * 16 + lrow;
            float b = bias[col];
            for (int r = 0; r < 4; ++r) {
                int row = bm * 64 + wr + mi * 16 + rbase + r;
                if (row < Mreal) {
                    float v = acc[mi][nj][r] + b;
                    Cout[(long)row * Nt + col] = v > 0.f ? v : 0.f;
                }
            }
        }
    }
}

extern "C" void kernel_launch(void* const* d_in, const int* in_sizes, int n_in,
                              void* d_out, int out_size, void* d_ws, size_t ws_size,
                              hipStream_t stream) {
    const float* x     = (const float*)d_in[0];
    const int*   eidx  = (const int*)  d_in[1];   // [2, E] int32
    const float* attr  = (const float*)d_in[2];
    const float* wrel  = (const float*)d_in[3];   // [3,256,256]
    const float* brel  = (const float*)d_in[4];   // [3,256]
    const float* wroot = (const float*)d_in[5];   // [3,256,256]
    const float* wout  = (const float*)d_in[6];   // [256,128]
    const float* bout  = (const float*)d_in[7];   // [128]
    const int* src = eidx;
    const int* dst = eidx + NEDGE;

    char* ws = (char*)d_ws;
    float* hA  = (float*)ws;  ws += (size_t)MPAD * HDIM * 4;
    float* hB  = (float*)ws;  ws += (size_t)MPAD * HDIM * 4;
    float* agg = (float*)ws;  ws += (size_t)MPAD * HDIM * 4;
    int*   deg     = (int*)ws;   ws += (size_t)NREAL * 4;
    int*   rowptr  = (int*)ws;   ws += (size_t)(NREAL + 1) * 4;
    int*   cursor  = (int*)ws;   ws += (size_t)NREAL * 4;
    int*   csr_src = (int*)ws;   ws += (size_t)NEDGE * 4;
    float* csr_attr= (float*)ws; ws += (size_t)NEDGE * 4;

    hipMemsetAsync(deg, 0, (size_t)NREAL * 4, stream);
    k_degree<<<(NEDGE + 255) / 256, 256, 0, stream>>>(dst, deg);
    k_scan<<<1, 1024, 0, stream>>>(deg, rowptr, cursor);
    k_fill<<<(NEDGE + 255) / 256, 256, 0, stream>>>(src, dst, attr, cursor, csr_src, csr_attr);
    k_padcopy<<<MPAD / 4, 256, 0, stream>>>(x, hA);

    float* hc = hA;
    float* hn = hB;
    for (int l = 0; l < 3; ++l) {
        k_aggregate<<<MPAD, 256, 0, stream>>>(hc, rowptr, csr_src, csr_attr, agg);
        k_gemm<<<dim3(313, 4), 256, 0, stream>>>(
            agg, hc,
            wrel + (size_t)l * HDIM * HDIM, wroot + (size_t)l * HDIM * HDIM,
            brel + (size_t)l * HDIM, hn, HDIM, MPAD);
        float* tmp = hc; hc = hn; hn = tmp;
    }
    k_gemm<<<dim3(313, 2), 256, 0, stream>>>(
        hc, nullptr, wout, nullptr, bout, (float*)d_out, ODIM, NREAL);
}

// Round 2
// 304.599 us; speedup vs baseline: 1.1295x; 1.1295x over previous
//
#include <hip/hip_runtime.h>

#define NREAL 20000
#define MPAD  20032      // 313 * 64
#define HDIM  256
#define ODIM  128
#define NEDGE 320000
#define SCAN_B 20        // ceil(NREAL/1024)

typedef __attribute__((ext_vector_type(4))) float f32x4;
typedef __attribute__((ext_vector_type(8))) short s16x8;
typedef __attribute__((ext_vector_type(4))) unsigned short u16x4;
typedef unsigned short u16;

__device__ inline u16 f2bf(float f) {
    unsigned int u = __float_as_uint(f);
    return (u16)((u + 0x7FFFu + ((u >> 16) & 1u)) >> 16);
}
__device__ inline float bf2f(u16 s) { return __uint_as_float(((unsigned)s) << 16); }

// ---------------- CSR build ----------------
__global__ void k_degree(const int* __restrict__ dst, int* __restrict__ deg) {
    int e = blockIdx.x * 256 + threadIdx.x;
    if (e < NEDGE) atomicAdd(&deg[dst[e]], 1);
}

__global__ __launch_bounds__(1024) void k_blocksum(const int* __restrict__ deg,
                                                   int* __restrict__ bsum) {
    __shared__ int red[16];
    int b = blockIdx.x, t = threadIdx.x;
    int i = b * 1024 + t;
    int v = (i < NREAL) ? deg[i] : 0;
    for (int off = 32; off; off >>= 1) v += __shfl_down(v, off);
    if ((t & 63) == 0) red[t >> 6] = v;
    __syncthreads();
    if (t < 16) {
        int s = red[t];
        for (int off = 8; off; off >>= 1) s += __shfl_down(s, off);
        if (t == 0) bsum[b] = s;
    }
}

__global__ void k_scansmall(const int* __restrict__ bsum, int* __restrict__ boff) {
    int t = threadIdx.x;  // one wave (64)
    int v = (t < SCAN_B) ? bsum[t] : 0;
    int orig = v;
    for (int off = 1; off < 64; off <<= 1) {
        int u = __shfl_up(v, off);
        if (t >= off) v += u;
    }
    if (t < SCAN_B) boff[t] = v - orig;
}

__global__ __launch_bounds__(1024) void k_scanfinal(const int* __restrict__ deg,
                                                    const int* __restrict__ boff,
                                                    int* __restrict__ rowptr,
                                                    int* __restrict__ cursor) {
    __shared__ int sm[1024];
    int b = blockIdx.x, t = threadIdx.x;
    int i = b * 1024 + t;
    int v = (i < NREAL) ? deg[i] : 0;
    sm[t] = v;
    __syncthreads();
    for (int off = 1; off < 1024; off <<= 1) {
        int u = (t >= off) ? sm[t - off] : 0;
        __syncthreads();
        if (t >= off) sm[t] += u;
        __syncthreads();
    }
    if (i < NREAL) {
        int excl = boff[b] + sm[t] - v;
        rowptr[i] = excl;
        cursor[i] = excl;
    }
    if (b == 0 && t == 0) rowptr[NREAL] = NEDGE;
}

__global__ void k_fill(const int* __restrict__ src, const int* __restrict__ dst,
                       const float* __restrict__ attr, int* __restrict__ cursor,
                       int* __restrict__ csr_src, float* __restrict__ csr_attr) {
    int e = blockIdx.x * 256 + threadIdx.x;
    if (e < NEDGE) {
        int d = dst[e];
        int p = atomicAdd(&cursor[d], 1);
        csr_src[p]  = src[e];
        csr_attr[p] = attr[e];
    }
}

// ---------------- pad-copy + split-convert x ----------------
__global__ void k_padconv(const float* __restrict__ x, float* __restrict__ h,
                          u16* __restrict__ hhi, u16* __restrict__ hlo) {
    long gid  = (long)blockIdx.x * 256 + threadIdx.x;
    long base = gid * 4;
    if (base >= (long)MPAD * HDIM) return;
    long row = base >> 8;
    f32x4 v = {0.f, 0.f, 0.f, 0.f};
    if (row < NREAL) v = *(const f32x4*)(x + base);
    *(f32x4*)(h + base) = v;
    u16x4 hi, lo;
    for (int j = 0; j < 4; ++j) {
        u16 hv = f2bf(v[j]);
        hi[j] = hv;
        lo[j] = f2bf(v[j] - bf2f(hv));
    }
    *(u16x4*)(hhi + base) = hi;
    *(u16x4*)(hlo + base) = lo;
}

// ---------------- weight transpose + bf16 convert ----------------
__global__ void k_wconv(const float* __restrict__ wrel, const float* __restrict__ wroot,
                        const float* __restrict__ wout,
                        u16* __restrict__ brelT, u16* __restrict__ brootT,
                        u16* __restrict__ boutT) {
    int i = blockIdx.x * 256 + threadIdx.x;
    if (i < 3 * 256 * 256) {
        int l = i >> 16, r = i & 65535, n = r >> 8, k = r & 255;
        brelT[i]  = f2bf(wrel [l * 65536 + k * 256 + n]);
        brootT[i] = f2bf(wroot[l * 65536 + k * 256 + n]);
    }
    if (i < 128 * 256) {
        int n = i >> 8, k = i & 255;
        boutT[i] = f2bf(wout[k * 128 + n]);
    }
}

// ---------------- aggregation: wave per node, f32x4 per lane ----------------
__global__ __launch_bounds__(256) void k_aggregate(
    const float* __restrict__ h, const int* __restrict__ rowptr,
    const int* __restrict__ csr_src, const float* __restrict__ csr_attr,
    u16* __restrict__ agg_hi, u16* __restrict__ agg_lo)
{
    const int node = blockIdx.x * 4 + (threadIdx.x >> 6);
    const int lane = threadIdx.x & 63;
    f32x4 acc = {0.f, 0.f, 0.f, 0.f};
    if (node < NREAL) {
        const int beg = rowptr[node], end = rowptr[node + 1];
        for (int c = beg; c < end; c += 64) {
            int m = end - c; if (m > 64) m = 64;
            int idx = c + (lane < m ? lane : m - 1);
            int   sj = csr_src[idx];
            float aj = csr_attr[idx];
            #pragma unroll 4
            for (int j = 0; j < m; ++j) {
                int   s = __shfl(sj, j);
                float a = __shfl(aj, j);
                f32x4 v = *(const f32x4*)(h + (long)s * HDIM + lane * 4);
                acc[0] += a * v[0];
                acc[1] += a * v[1];
                acc[2] += a * v[2];
                acc[3] += a * v[3];
            }
        }
    }
    long base = (long)node * HDIM + lane * 4;
    u16x4 hi, lo;
    for (int j = 0; j < 4; ++j) {
        u16 hv = f2bf(acc[j]);
        hi[j] = hv;
        lo[j] = f2bf(acc[j] - bf2f(hv));
    }
    *(u16x4*)(agg_hi + base) = hi;
    *(u16x4*)(agg_lo + base) = lo;
}

// ---------------- GEMM: C = relu(A1@B1 [+ A2@B2] + bias) ----------------
// A split bf16 [MPAD,256]; B pre-transposed bf16 [Nt,256].
__global__ __launch_bounds__(256) void k_gemm(
    const u16* __restrict__ Ahi1, const u16* __restrict__ Alo1,
    const u16* __restrict__ Ahi2, const u16* __restrict__ Alo2,
    const u16* __restrict__ BT1,  const u16* __restrict__ BT2,
    const float* __restrict__ bias,
    float* __restrict__ h_out, u16* __restrict__ hhi, u16* __restrict__ hlo,
    float* __restrict__ final_out, int Nt)
{
    __shared__ __align__(16) u16 Ah[64][72];
    __shared__ __align__(16) u16 Al[64][72];
    __shared__ __align__(16) u16 Bs[64][72];

    const int t    = threadIdx.x;
    const int bm   = blockIdx.x, bn = blockIdx.y;
    const int lane = t & 63;
    const int wave = t >> 6;
    const int wr   = (wave >> 1) * 32;
    const int wc   = (wave & 1) * 32;
    const int lrow = lane & 15;
    const int lk   = (lane >> 4) * 8;

    f32x4 acc[2][2];
    for (int i = 0; i < 2; ++i)
        for (int j = 0; j < 2; ++j)
            for (int r = 0; r < 4; ++r) acc[i][j][r] = 0.f;

    const int srow0 = t >> 3;        // 0..31
    const int scol  = (t & 7) * 8;   // 0..56 step 8

    const int nmat = Ahi2 ? 2 : 1;
    for (int mat = 0; mat < nmat; ++mat) {
        const u16* Ah_g = mat ? Ahi2 : Ahi1;
        const u16* Al_g = mat ? Alo2 : Alo1;
        const u16* B_g  = mat ? BT2  : BT1;
        for (int k0 = 0; k0 < HDIM; k0 += 64) {
            __syncthreads();
            #pragma unroll
            for (int i = 0; i < 2; ++i) {
                int row = srow0 + i * 32;
                long ga = (long)(bm * 64 + row) * HDIM + k0 + scol;
                long gb = (long)(bn * 64 + row) * HDIM + k0 + scol;
                *(s16x8*)&Ah[row][scol] = *(const s16x8*)(Ah_g + ga);
                *(s16x8*)&Al[row][scol] = *(const s16x8*)(Al_g + ga);
                *(s16x8*)&Bs[row][scol] = *(const s16x8*)(B_g  + gb);
            }
            __syncthreads();
            #pragma unroll
            for (int kk = 0; kk < 2; ++kk) {
                int kb = kk * 32 + lk;
                s16x8 b0 = *(const s16x8*)&Bs[wc + lrow     ][kb];
                s16x8 b1 = *(const s16x8*)&Bs[wc + 16 + lrow][kb];
                #pragma unroll
                for (int mi = 0; mi < 2; ++mi) {
                    s16x8 ah = *(const s16x8*)&Ah[wr + mi * 16 + lrow][kb];
                    s16x8 al = *(const s16x8*)&Al[wr + mi * 16 + lrow][kb];
                    acc[mi][0] = __builtin_amdgcn_mfma_f32_16x16x32_bf16(ah, b0, acc[mi][0], 0, 0, 0);
                    acc[mi][0] = __builtin_amdgcn_mfma_f32_16x16x32_bf16(al, b0, acc[mi][0], 0, 0, 0);
                    acc[mi][1] = __builtin_amdgcn_mfma_f32_16x16x32_bf16(ah, b1, acc[mi][1], 0, 0, 0);
                    acc[mi][1] = __builtin_amdgcn_mfma_f32_16x16x32_bf16(al, b1, acc[mi][1], 0, 0, 0);
                }
            }
        }
    }

    // epilogue
    const int rb = (lane >> 4) * 4;
    for (int mi = 0; mi < 2; ++mi) {
        for (int nj = 0; nj < 2; ++nj) {
            int col = bn * 64 + wc + nj * 16 + lrow;
            float bsv = bias[col];
            for (int r = 0; r < 4; ++r) {
                int row = bm * 64 + wr + mi * 16 + rb + r;
                float v = acc[mi][nj][r] + bsv;
                v = v > 0.f ? v : 0.f;
                if (final_out) {
                    if (row < NREAL) final_out[(long)row * Nt + col] = v;
                } else {
                    long o = (long)row * HDIM + col;
                    h_out[o] = v;
                    u16 hv = f2bf(v);
                    hhi[o] = hv;
                    hlo[o] = f2bf(v - bf2f(hv));
                }
            }
        }
    }
}

static inline char* align256(char* p) {
    return (char*)(((size_t)p + 255) & ~(size_t)255);
}

extern "C" void kernel_launch(void* const* d_in, const int* in_sizes, int n_in,
                              void* d_out, int out_size, void* d_ws, size_t ws_size,
                              hipStream_t stream) {
    const float* x     = (const float*)d_in[0];
    const int*   eidx  = (const int*)  d_in[1];
    const float* attr  = (const float*)d_in[2];
    const float* wrel  = (const float*)d_in[3];
    const float* brel  = (const float*)d_in[4];
    const float* wroot = (const float*)d_in[5];
    const float* wout  = (const float*)d_in[6];
    const float* bout  = (const float*)d_in[7];
    const int* src = eidx;
    const int* dst = eidx + NEDGE;

    char* ws = (char*)d_ws;
    float* h = (float*)ws;        ws = align256(ws + (size_t)MPAD * HDIM * 4);
    u16* hhiA = (u16*)ws;         ws = align256(ws + (size_t)MPAD * HDIM * 2);
    u16* hloA = (u16*)ws;         ws = align256(ws + (size_t)MPAD * HDIM * 2);
    u16* hhiB = (u16*)ws;         ws = align256(ws + (size_t)MPAD * HDIM * 2);
    u16* hloB = (u16*)ws;         ws = align256(ws + (size_t)MPAD * HDIM * 2);
    u16* agg_hi = (u16*)ws;       ws = align256(ws + (size_t)MPAD * HDIM * 2);
    u16* agg_lo = (u16*)ws;       ws = align256(ws + (size_t)MPAD * HDIM * 2);
    u16* brelT  = (u16*)ws;       ws = align256(ws + (size_t)3 * 65536 * 2);
    u16* brootT = (u16*)ws;       ws = align256(ws + (size_t)3 * 65536 * 2);
    u16* boutT  = (u16*)ws;       ws = align256(ws + (size_t)128 * 256 * 2);
    int* deg    = (int*)ws;       ws = align256(ws + (size_t)NREAL * 4);
    int* rowptr = (int*)ws;       ws = align256(ws + (size_t)(NREAL + 1) * 4);
    int* cursor = (int*)ws;       ws = align256(ws + (size_t)NREAL * 4);
    int* bsum   = (int*)ws;       ws = align256(ws + (size_t)SCAN_B * 4);
    int* boff   = (int*)ws;       ws = align256(ws + (size_t)SCAN_B * 4);
    int* csr_src = (int*)ws;      ws = align256(ws + (size_t)NEDGE * 4);
    float* csr_attr = (float*)ws; ws = align256(ws + (size_t)NEDGE * 4);

    hipMemsetAsync(deg, 0, (size_t)NREAL * 4, stream);
    k_degree<<<(NEDGE + 255) / 256, 256, 0, stream>>>(dst, deg);
    k_blocksum<<<SCAN_B, 1024, 0, stream>>>(deg, bsum);
    k_scansmall<<<1, 64, 0, stream>>>(bsum, boff);
    k_scanfinal<<<SCAN_B, 1024, 0, stream>>>(deg, boff, rowptr, cursor);
    k_fill<<<(NEDGE + 255) / 256, 256, 0, stream>>>(src, dst, attr, cursor, csr_src, csr_attr);
    k_padconv<<<MPAD * HDIM / 4 / 256, 256, 0, stream>>>(x, h, hhiA, hloA);
    k_wconv<<<(3 * 65536 + 255) / 256, 256, 0, stream>>>(wrel, wroot, wout, brelT, brootT, boutT);

    u16* hhi_c = hhiA; u16* hlo_c = hloA;
    u16* hhi_n = hhiB; u16* hlo_n = hloB;
    for (int l = 0; l < 3; ++l) {
        k_aggregate<<<MPAD / 4, 256, 0, stream>>>(h, rowptr, csr_src, csr_attr, agg_hi, agg_lo);
        k_gemm<<<dim3(313, 4), 256, 0, stream>>>(
            agg_hi, agg_lo, hhi_c, hlo_c,
            brelT + (size_t)l * 65536, brootT + (size_t)l * 65536,
            brel + (size_t)l * HDIM,
            h, hhi_n, hlo_n, nullptr, HDIM);
        u16* tp;
        tp = hhi_c; hhi_c = hhi_n; hhi_n = tp;
        tp = hlo_c; hlo_c = hlo_n; hlo_n = tp;
    }
    k_gemm<<<dim3(313, 2), 256, 0, stream>>>(
        hhi_c, hlo_c, nullptr, nullptr, boutT, nullptr, bout,
        nullptr, nullptr, nullptr, (float*)d_out, ODIM);
}

// Round 3
// 238.147 us; speedup vs baseline: 1.4447x; 1.2790x over previous
//
#include <hip/hip_runtime.h>

#define NREAL 20000
#define MPAD  20032      // 313 * 64
#define HDIM  256
#define ODIM  128
#define NEDGE 320000
#define SCAN_B 20        // ceil(NREAL/1024)

typedef __attribute__((ext_vector_type(4))) float f32x4;
typedef __attribute__((ext_vector_type(8))) short s16x8;
typedef __attribute__((ext_vector_type(4))) unsigned short u16x4;
typedef unsigned short u16;

__device__ inline u16 f2bf(float f) {
    unsigned int u = __float_as_uint(f);
    return (u16)((u + 0x7FFFu + ((u >> 16) & 1u)) >> 16);
}
__device__ inline float bf2f(u16 s) { return __uint_as_float(((unsigned)s) << 16); }

// ---------------- CSR build ----------------
__global__ void k_degree(const int* __restrict__ dst, int* __restrict__ deg) {
    int e = blockIdx.x * 256 + threadIdx.x;
    if (e < NEDGE) atomicAdd(&deg[dst[e]], 1);
}

__global__ __launch_bounds__(1024) void k_blocksum(const int* __restrict__ deg,
                                                   int* __restrict__ bsum) {
    __shared__ int red[16];
    int b = blockIdx.x, t = threadIdx.x;
    int i = b * 1024 + t;
    int v = (i < NREAL) ? deg[i] : 0;
    for (int off = 32; off; off >>= 1) v += __shfl_down(v, off);
    if ((t & 63) == 0) red[t >> 6] = v;
    __syncthreads();
    if (t < 16) {
        int s = red[t];
        for (int off = 8; off; off >>= 1) s += __shfl_down(s, off);
        if (t == 0) bsum[b] = s;
    }
}

__global__ void k_scansmall(const int* __restrict__ bsum, int* __restrict__ boff) {
    int t = threadIdx.x;  // one wave (64)
    int v = (t < SCAN_B) ? bsum[t] : 0;
    int orig = v;
    for (int off = 1; off < 64; off <<= 1) {
        int u = __shfl_up(v, off);
        if (t >= off) v += u;
    }
    if (t < SCAN_B) boff[t] = v - orig;
}

__global__ __launch_bounds__(1024) void k_scanfinal(const int* __restrict__ deg,
                                                    const int* __restrict__ boff,
                                                    int* __restrict__ rowptr,
                                                    int* __restrict__ cursor) {
    __shared__ int sm[1024];
    int b = blockIdx.x, t = threadIdx.x;
    int i = b * 1024 + t;
    int v = (i < NREAL) ? deg[i] : 0;
    sm[t] = v;
    __syncthreads();
    for (int off = 1; off < 1024; off <<= 1) {
        int u = (t >= off) ? sm[t - off] : 0;
        __syncthreads();
        if (t >= off) sm[t] += u;
        __syncthreads();
    }
    if (i < NREAL) {
        int excl = boff[b] + sm[t] - v;
        rowptr[i] = excl;
        cursor[i] = excl;
    }
    if (b == 0 && t == 0) rowptr[NREAL] = NEDGE;
}

__global__ void k_fill(const int* __restrict__ src, const int* __restrict__ dst,
                       const float* __restrict__ attr, int* __restrict__ cursor,
                       int* __restrict__ csr_src, float* __restrict__ csr_attr) {
    int e = blockIdx.x * 256 + threadIdx.x;
    if (e < NEDGE) {
        int d = dst[e];
        int p = atomicAdd(&cursor[d], 1);
        csr_src[p]  = src[e];
        csr_attr[p] = attr[e];
    }
}

// ---------------- pad-copy + split-convert x (bf16 hi/lo only) ----------------
__global__ void k_padconv(const float* __restrict__ x,
                          u16* __restrict__ hhi, u16* __restrict__ hlo) {
    long gid  = (long)blockIdx.x * 256 + threadIdx.x;
    long base = gid * 4;
    if (base >= (long)MPAD * HDIM) return;
    long row = base >> 8;
    f32x4 v = {0.f, 0.f, 0.f, 0.f};
    if (row < NREAL) v = *(const f32x4*)(x + base);
    u16x4 hi, lo;
    for (int j = 0; j < 4; ++j) {
        u16 hv = f2bf(v[j]);
        hi[j] = hv;
        lo[j] = f2bf(v[j] - bf2f(hv));
    }
    *(u16x4*)(hhi + base) = hi;
    *(u16x4*)(hlo + base) = lo;
}

// ---------------- weight transpose + bf16 convert ----------------
__global__ void k_wconv(const float* __restrict__ wrel, const float* __restrict__ wroot,
                        const float* __restrict__ wout,
                        u16* __restrict__ brelT, u16* __restrict__ brootT,
                        u16* __restrict__ boutT) {
    int i = blockIdx.x * 256 + threadIdx.x;
    if (i < 3 * 256 * 256) {
        int l = i >> 16, r = i & 65535, n = r >> 8, k = r & 255;
        brelT[i]  = f2bf(wrel [l * 65536 + k * 256 + n]);
        brootT[i] = f2bf(wroot[l * 65536 + k * 256 + n]);
    }
    if (i < 128 * 256) {
        int n = i >> 8, k = i & 255;
        boutT[i] = f2bf(wout[k * 128 + n]);
    }
}

// ---------------- aggregation: wave per node, 2 edges/iter, bf16 gather ----------------
__global__ __launch_bounds__(256) void k_aggregate(
    const u16* __restrict__ hbf, const int* __restrict__ rowptr,
    const int* __restrict__ csr_src, const float* __restrict__ csr_attr,
    u16* __restrict__ agg_hi, u16* __restrict__ agg_lo)
{
    const int node = blockIdx.x * 4 + (threadIdx.x >> 6);
    const int lane = threadIdx.x & 63;
    const int half = lane >> 5;        // which edge of the pair
    const int col8 = (lane & 31) * 8;  // 8 bf16 columns per lane
    float acc[8] = {0.f,0.f,0.f,0.f,0.f,0.f,0.f,0.f};
    if (node < NREAL) {
        const int beg = rowptr[node], end = rowptr[node + 1];
        for (int c = beg; c < end; c += 64) {
            int m = end - c; if (m > 64) m = 64;
            int idx = c + (lane < m ? lane : 0);
            int   sj = csr_src[idx];
            float aj = (lane < m) ? csr_attr[idx] : 0.f;
            int npair = (m + 1) >> 1;
            #pragma unroll 4
            for (int p = 0; p < npair; ++p) {
                int sel = 2 * p + half;          // edge slot in this chunk
                int   s = __shfl(sj, sel);       // a==0 when sel==m (odd tail)
                float a = __shfl(aj, sel);
                s16x8 v = *(const s16x8*)(hbf + (long)s * HDIM + col8);
                #pragma unroll
                for (int q = 0; q < 8; ++q)
                    acc[q] += a * bf2f((u16)v[q]);
            }
        }
    }
    #pragma unroll
    for (int q = 0; q < 8; ++q)
        acc[q] += __shfl_xor(acc[q], 32);
    s16x8 hv, lv;
    #pragma unroll
    for (int q = 0; q < 8; ++q) {
        u16 h8 = f2bf(acc[q]);
        hv[q] = (short)h8;
        lv[q] = (short)f2bf(acc[q] - bf2f(h8));
    }
    long base = (long)node * HDIM + col8;
    if (half == 0) *(s16x8*)(agg_hi + base) = hv;
    else           *(s16x8*)(agg_lo + base) = lv;
}

// ---------------- GEMM: C = relu(A1@B1 [+ A2@B2] + bias) ----------------
// A split bf16 [MPAD,256]; B pre-transposed bf16 [Nt,256].
__global__ __launch_bounds__(256) void k_gemm(
    const u16* __restrict__ Ahi1, const u16* __restrict__ Alo1,
    const u16* __restrict__ Ahi2, const u16* __restrict__ Alo2,
    const u16* __restrict__ BT1,  const u16* __restrict__ BT2,
    const float* __restrict__ bias,
    u16* __restrict__ hhi, u16* __restrict__ hlo,
    float* __restrict__ final_out, int Nt)
{
    __shared__ __align__(16) u16 Ah[64][72];
    __shared__ __align__(16) u16 Al[64][72];
    __shared__ __align__(16) u16 Bs[64][72];

    const int t    = threadIdx.x;
    const int bm   = blockIdx.x, bn = blockIdx.y;
    const int lane = t & 63;
    const int wave = t >> 6;
    const int wr   = (wave >> 1) * 32;
    const int wc   = (wave & 1) * 32;
    const int lrow = lane & 15;
    const int lk   = (lane >> 4) * 8;

    f32x4 acc[2][2];
    for (int i = 0; i < 2; ++i)
        for (int j = 0; j < 2; ++j)
            for (int r = 0; r < 4; ++r) acc[i][j][r] = 0.f;

    const int srow0 = t >> 3;        // 0..31
    const int scol  = (t & 7) * 8;   // 0..56 step 8

    const int nmat = Ahi2 ? 2 : 1;
    for (int mat = 0; mat < nmat; ++mat) {
        const u16* Ah_g = mat ? Ahi2 : Ahi1;
        const u16* Al_g = mat ? Alo2 : Alo1;
        const u16* B_g  = mat ? BT2  : BT1;
        for (int k0 = 0; k0 < HDIM; k0 += 64) {
            __syncthreads();
            #pragma unroll
            for (int i = 0; i < 2; ++i) {
                int row = srow0 + i * 32;
                long ga = (long)(bm * 64 + row) * HDIM + k0 + scol;
                long gb = (long)(bn * 64 + row) * HDIM + k0 + scol;
                *(s16x8*)&Ah[row][scol] = *(const s16x8*)(Ah_g + ga);
                *(s16x8*)&Al[row][scol] = *(const s16x8*)(Al_g + ga);
                *(s16x8*)&Bs[row][scol] = *(const s16x8*)(B_g  + gb);
            }
            __syncthreads();
            #pragma unroll
            for (int kk = 0; kk < 2; ++kk) {
                int kb = kk * 32 + lk;
                s16x8 b0 = *(const s16x8*)&Bs[wc + lrow     ][kb];
                s16x8 b1 = *(const s16x8*)&Bs[wc + 16 + lrow][kb];
                #pragma unroll
                for (int mi = 0; mi < 2; ++mi) {
                    s16x8 ah = *(const s16x8*)&Ah[wr + mi * 16 + lrow][kb];
                    s16x8 al = *(const s16x8*)&Al[wr + mi * 16 + lrow][kb];
                    acc[mi][0] = __builtin_amdgcn_mfma_f32_16x16x32_bf16(ah, b0, acc[mi][0], 0, 0, 0);
                    acc[mi][0] = __builtin_amdgcn_mfma_f32_16x16x32_bf16(al, b0, acc[mi][0], 0, 0, 0);
                    acc[mi][1] = __builtin_amdgcn_mfma_f32_16x16x32_bf16(ah, b1, acc[mi][1], 0, 0, 0);
                    acc[mi][1] = __builtin_amdgcn_mfma_f32_16x16x32_bf16(al, b1, acc[mi][1], 0, 0, 0);
                }
            }
        }
    }

    // epilogue
    const int rb = (lane >> 4) * 4;
    for (int mi = 0; mi < 2; ++mi) {
        for (int nj = 0; nj < 2; ++nj) {
            int col = bn * 64 + wc + nj * 16 + lrow;
            float bsv = bias[col];
            for (int r = 0; r < 4; ++r) {
                int row = bm * 64 + wr + mi * 16 + rb + r;
                float v = acc[mi][nj][r] + bsv;
                v = v > 0.f ? v : 0.f;
                if (final_out) {
                    if (row < NREAL) final_out[(long)row * Nt + col] = v;
                } else {
                    long o = (long)row * HDIM + col;
                    u16 hv = f2bf(v);
                    hhi[o] = hv;
                    hlo[o] = f2bf(v - bf2f(hv));
                }
            }
        }
    }
}

static inline char* align256(char* p) {
    return (char*)(((size_t)p + 255) & ~(size_t)255);
}

extern "C" void kernel_launch(void* const* d_in, const int* in_sizes, int n_in,
                              void* d_out, int out_size, void* d_ws, size_t ws_size,
                              hipStream_t stream) {
    const float* x     = (const float*)d_in[0];
    const int*   eidx  = (const int*)  d_in[1];
    const float* attr  = (const float*)d_in[2];
    const float* wrel  = (const float*)d_in[3];
    const float* brel  = (const float*)d_in[4];
    const float* wroot = (const float*)d_in[5];
    const float* wout  = (const float*)d_in[6];
    const float* bout  = (const float*)d_in[7];
    const int* src = eidx;
    const int* dst = eidx + NEDGE;

    char* ws = (char*)d_ws;
    u16* hhiA = (u16*)ws;         ws = align256(ws + (size_t)MPAD * HDIM * 2);
    u16* hloA = (u16*)ws;         ws = align256(ws + (size_t)MPAD * HDIM * 2);
    u16* hhiB = (u16*)ws;         ws = align256(ws + (size_t)MPAD * HDIM * 2);
    u16* hloB = (u16*)ws;         ws = align256(ws + (size_t)MPAD * HDIM * 2);
    u16* agg_hi = (u16*)ws;       ws = align256(ws + (size_t)MPAD * HDIM * 2);
    u16* agg_lo = (u16*)ws;       ws = align256(ws + (size_t)MPAD * HDIM * 2);
    u16* brelT  = (u16*)ws;       ws = align256(ws + (size_t)3 * 65536 * 2);
    u16* brootT = (u16*)ws;       ws = align256(ws + (size_t)3 * 65536 * 2);
    u16* boutT  = (u16*)ws;       ws = align256(ws + (size_t)128 * 256 * 2);
    int* deg    = (int*)ws;       ws = align256(ws + (size_t)NREAL * 4);
    int* rowptr = (int*)ws;       ws = align256(ws + (size_t)(NREAL + 1) * 4);
    int* cursor = (int*)ws;       ws = align256(ws + (size_t)NREAL * 4);
    int* bsum   = (int*)ws;       ws = align256(ws + (size_t)SCAN_B * 4);
    int* boff   = (int*)ws;       ws = align256(ws + (size_t)SCAN_B * 4);
    int* csr_src = (int*)ws;      ws = align256(ws + (size_t)NEDGE * 4);
    float* csr_attr = (float*)ws; ws = align256(ws + (size_t)NEDGE * 4);

    hipMemsetAsync(deg, 0, (size_t)NREAL * 4, stream);
    k_degree<<<(NEDGE + 255) / 256, 256, 0, stream>>>(dst, deg);
    k_blocksum<<<SCAN_B, 1024, 0, stream>>>(deg, bsum);
    k_scansmall<<<1, 64, 0, stream>>>(bsum, boff);
    k_scanfinal<<<SCAN_B, 1024, 0, stream>>>(deg, boff, rowptr, cursor);
    k_fill<<<(NEDGE + 255) / 256, 256, 0, stream>>>(src, dst, attr, cursor, csr_src, csr_attr);
    k_padconv<<<MPAD * HDIM / 4 / 256, 256, 0, stream>>>(x, hhiA, hloA);
    k_wconv<<<(3 * 65536 + 255) / 256, 256, 0, stream>>>(wrel, wroot, wout, brelT, brootT, boutT);

    u16* hhi_c = hhiA; u16* hlo_c = hloA;
    u16* hhi_n = hhiB; u16* hlo_n = hloB;
    for (int l = 0; l < 3; ++l) {
        k_aggregate<<<MPAD / 4, 256, 0, stream>>>(hhi_c, rowptr, csr_src, csr_attr, agg_hi, agg_lo);
        k_gemm<<<dim3(313, 4), 256, 0, stream>>>(
            agg_hi, agg_lo, hhi_c, hlo_c,
            brelT + (size_t)l * 65536, brootT + (size_t)l * 65536,
            brel + (size_t)l * HDIM,
            hhi_n, hlo_n, nullptr, HDIM);
        u16* tp;
        tp = hhi_c; hhi_c = hhi_n; hhi_n = tp;
        tp = hlo_c; hlo_c = hlo_n; hlo_n = tp;
    }
    k_gemm<<<dim3(313, 2), 256, 0, stream>>>(
        hhi_c, hlo_c, nullptr, nullptr, boutT, nullptr, bout,
        nullptr, nullptr, (float*)d_out, ODIM);
}

// Round 5
// 236.302 us; speedup vs baseline: 1.4560x; 1.0078x over previous
//
#include <hip/hip_runtime.h>

#define NREAL 20000
#define MPAD  20032      // 313 * 64
#define HDIM  256
#define ODIM  128
#define NEDGE 320000
#define SCAN_B 20        // ceil(NREAL/1024)
#define PREP_B (MPAD * HDIM / 4 / 256)   // 5008 pad-convert blocks

typedef __attribute__((ext_vector_type(4))) float f32x4;
typedef __attribute__((ext_vector_type(8))) short s16x8;
typedef __attribute__((ext_vector_type(4))) unsigned short u16x4;
typedef unsigned short u16;
typedef unsigned long long u64;

__device__ inline u16 f2bf(float f) {
    unsigned int u = __float_as_uint(f);
    return (u16)((u + 0x7FFFu + ((u >> 16) & 1u)) >> 16);
}
__device__ inline float bf2f(u16 s) { return __uint_as_float(((unsigned)s) << 16); }

// ---------------- CSR build ----------------
__global__ void k_degree(const int* __restrict__ dst, int* __restrict__ deg) {
    int e = blockIdx.x * 256 + threadIdx.x;
    if (e < NEDGE) atomicAdd(&deg[dst[e]], 1);
}

__global__ __launch_bounds__(1024) void k_blocksum(const int* __restrict__ deg,
                                                   int* __restrict__ bsum) {
    __shared__ int red[16];
    int b = blockIdx.x, t = threadIdx.x;
    int i = b * 1024 + t;
    int v = (i < NREAL) ? deg[i] : 0;
    for (int off = 32; off; off >>= 1) v += __shfl_down(v, off);
    if ((t & 63) == 0) red[t >> 6] = v;
    __syncthreads();
    if (t < 16) {
        int s = red[t];
        for (int off = 8; off; off >>= 1) s += __shfl_down(s, off);
        if (t == 0) bsum[b] = s;
    }
}

__global__ void k_scansmall(const int* __restrict__ bsum, int* __restrict__ boff) {
    int t = threadIdx.x;  // one wave (64)
    int v = (t < SCAN_B) ? bsum[t] : 0;
    int orig = v;
    for (int off = 1; off < 64; off <<= 1) {
        int u = __shfl_up(v, off);
        if (t >= off) v += u;
    }
    if (t < SCAN_B) boff[t] = v - orig;
}

__global__ __launch_bounds__(1024) void k_scanfinal(const int* __restrict__ deg,
                                                    const int* __restrict__ boff,
                                                    int* __restrict__ rowptr,
                                                    int* __restrict__ cursor) {
    __shared__ int sm[1024];
    int b = blockIdx.x, t = threadIdx.x;
    int i = b * 1024 + t;
    int v = (i < NREAL) ? deg[i] : 0;
    sm[t] = v;
    __syncthreads();
    for (int off = 1; off < 1024; off <<= 1) {
        int u = (t >= off) ? sm[t - off] : 0;
        __syncthreads();
        if (t >= off) sm[t] += u;
        __syncthreads();
    }
    if (i < NREAL) {
        int excl = boff[b] + sm[t] - v;
        rowptr[i] = excl;
        cursor[i] = excl;
    }
    if (b == 0 && t == 0) rowptr[NREAL] = NEDGE;
}

__global__ void k_fill(const int* __restrict__ src, const int* __restrict__ dst,
                       const float* __restrict__ attr, int* __restrict__ cursor,
                       u64* __restrict__ csr_edge) {
    int e = blockIdx.x * 256 + threadIdx.x;
    if (e < NEDGE) {
        int d = dst[e];
        int p = atomicAdd(&cursor[d], 1);
        csr_edge[p] = ((u64)__float_as_uint(attr[e]) << 32) | (unsigned)src[e];
    }
}

// ---------------- canonical segment sort: wave per node, odd-even transposition ----------------
// Makes CSR layout (and thus all downstream fp summation order) a deterministic
// function of the inputs, independent of k_fill's atomic scheduling order.
__global__ __launch_bounds__(256) void k_sortseg(const int* __restrict__ rowptr,
                                                 u64* __restrict__ csr_edge) {
    const int node = blockIdx.x * 4 + (threadIdx.x >> 6);
    const int lane = threadIdx.x & 63;
    if (node >= NREAL) return;
    const int beg = rowptr[node], end = rowptr[node + 1];
    const int m = end - beg;
    if (m <= 1) return;
    if (m <= 64) {
        u64 val = (lane < m) ? csr_edge[beg + lane] : ~0ull;
        #pragma unroll
        for (int ph = 0; ph < 64; ++ph) {
            int base = ph & 1;
            int partner = lane + (((lane ^ base) & 1) ? -1 : +1);
            if (partner < 0 || partner > 63) partner = lane;
            u64 p = __shfl(val, partner);
            if (partner != lane)
                val = (lane < partner) ? (val < p ? val : p) : (val > p ? val : p);
        }
        if (lane < m) csr_edge[beg + lane] = val;
    } else if (lane == 0) {
        // serial insertion sort (degree > 64: essentially never at Poisson(16))
        for (int i = beg + 1; i < end; ++i) {
            u64 key = csr_edge[i];
            int j = i - 1;
            while (j >= beg && csr_edge[j] > key) { csr_edge[j + 1] = csr_edge[j]; --j; }
            csr_edge[j + 1] = key;
        }
    }
}

// ---------------- prep: pad-convert x to bf16 + weight transpose/convert ----------------
__global__ void k_prep(const float* __restrict__ x, u16* __restrict__ hbf,
                       const float* __restrict__ wrel, const float* __restrict__ wroot,
                       const float* __restrict__ wout,
                       u16* __restrict__ brelT, u16* __restrict__ brootT,
                       u16* __restrict__ boutT) {
    int b = blockIdx.x;
    if (b < PREP_B) {
        long gid  = (long)b * 256 + threadIdx.x;
        long base = gid * 4;
        long row  = base >> 8;
        f32x4 v = {0.f, 0.f, 0.f, 0.f};
        if (row < NREAL) v = *(const f32x4*)(x + base);
        u16x4 hv;
        for (int j = 0; j < 4; ++j) hv[j] = f2bf(v[j]);
        *(u16x4*)(hbf + base) = hv;
    } else {
        int i = (b - PREP_B) * 256 + threadIdx.x;
        if (i < 3 * 256 * 256) {
            int l = i >> 16, r = i & 65535, n = r >> 8, k = r & 255;
            brelT[i]  = f2bf(wrel [l * 65536 + k * 256 + n]);
            brootT[i] = f2bf(wroot[l * 65536 + k * 256 + n]);
        }
        if (i < 128 * 256) {
            int n = i >> 8, k = i & 255;
            boutT[i] = f2bf(wout[k * 128 + n]);
        }
    }
}

// ---------------- aggregation: wave per node, 2 edges/iter, bf16 gather ----------------
__global__ __launch_bounds__(256) void k_aggregate(
    const u16* __restrict__ hbf, const int* __restrict__ rowptr,
    const u64* __restrict__ csr_edge, u16* __restrict__ agg)
{
    const int node = blockIdx.x * 4 + (threadIdx.x >> 6);
    const int lane = threadIdx.x & 63;
    const int half = lane >> 5;        // which edge of the pair
    const int col8 = (lane & 31) * 8;  // 8 bf16 columns per lane
    float acc[8] = {0.f,0.f,0.f,0.f,0.f,0.f,0.f,0.f};
    if (node < NREAL) {
        const int beg = rowptr[node], end = rowptr[node + 1];
        for (int c = beg; c < end; c += 64) {
            int m = end - c; if (m > 64) m = 64;
            u64 ej = csr_edge[c + (lane < m ? lane : 0)];
            int   sj = (int)(unsigned)ej;
            float aj = (lane < m) ? __uint_as_float((unsigned)(ej >> 32)) : 0.f;
            int npair = (m + 1) >> 1;
            #pragma unroll 4
            for (int p = 0; p < npair; ++p) {
                int sel = 2 * p + half;
                int   s = __shfl(sj, sel);      // aj==0 on the odd-tail slot
                float a = __shfl(aj, sel);
                s16x8 v = *(const s16x8*)(hbf + (long)s * HDIM + col8);
                #pragma unroll
                for (int q = 0; q < 8; ++q)
                    acc[q] += a * bf2f((u16)v[q]);
            }
        }
    }
    #pragma unroll
    for (int q = 0; q < 8; ++q)
        acc[q] += __shfl_xor(acc[q], 32);
    if (half == 0) {
        s16x8 hv;
        #pragma unroll
        for (int q = 0; q < 8; ++q) hv[q] = (short)f2bf(acc[q]);
        *(s16x8*)(agg + (long)node * HDIM + col8) = hv;
    }
}

// ---------------- GEMM: C = relu(A1@B1 [+ A2@B2] + bias), single bf16 ----------------
// A bf16 [MPAD,256]; B pre-transposed bf16 [Nt,256].
__global__ __launch_bounds__(256) void k_gemm(
    const u16* __restrict__ A1, const u16* __restrict__ A2,
    const u16* __restrict__ BT1, const u16* __restrict__ BT2,
    const float* __restrict__ bias,
    u16* __restrict__ hout, float* __restrict__ final_out, int Nt)
{
    __shared__ __align__(16) u16 As[64][72];
    __shared__ __align__(16) u16 Bs[64][72];

    const int t    = threadIdx.x;
    const int bm   = blockIdx.x, bn = blockIdx.y;
    const int lane = t & 63;
    const int wave = t >> 6;
    const int wr   = (wave >> 1) * 32;
    const int wc   = (wave & 1) * 32;
    const int lrow = lane & 15;
    const int lk   = (lane >> 4) * 8;

    f32x4 acc[2][2];
    for (int i = 0; i < 2; ++i)
        for (int j = 0; j < 2; ++j)
            for (int r = 0; r < 4; ++r) acc[i][j][r] = 0.f;

    const int srow0 = t >> 3;        // 0..31
    const int scol  = (t & 7) * 8;   // 0..56 step 8

    const int nmat = A2 ? 2 : 1;
    for (int mat = 0; mat < nmat; ++mat) {
        const u16* A_g = mat ? A2  : A1;
        const u16* B_g = mat ? BT2 : BT1;
        for (int k0 = 0; k0 < HDIM; k0 += 64) {
            __syncthreads();
            #pragma unroll
            for (int i = 0; i < 2; ++i) {
                int row = srow0 + i * 32;
                long ga = (long)(bm * 64 + row) * HDIM + k0 + scol;
                long gb = (long)(bn * 64 + row) * HDIM + k0 + scol;
                *(s16x8*)&As[row][scol] = *(const s16x8*)(A_g + ga);
                *(s16x8*)&Bs[row][scol] = *(const s16x8*)(B_g + gb);
            }
            __syncthreads();
            #pragma unroll
            for (int kk = 0; kk < 2; ++kk) {
                int kb = kk * 32 + lk;
                s16x8 b0 = *(const s16x8*)&Bs[wc + lrow     ][kb];
                s16x8 b1 = *(const s16x8*)&Bs[wc + 16 + lrow][kb];
                #pragma unroll
                for (int mi = 0; mi < 2; ++mi) {
                    s16x8 a = *(const s16x8*)&As[wr + mi * 16 + lrow][kb];
                    acc[mi][0] = __builtin_amdgcn_mfma_f32_16x16x32_bf16(a, b0, acc[mi][0], 0, 0, 0);
                    acc[mi][1] = __builtin_amdgcn_mfma_f32_16x16x32_bf16(a, b1, acc[mi][1], 0, 0, 0);
                }
            }
        }
    }

    // epilogue
    const int rb = (lane >> 4) * 4;
    for (int mi = 0; mi < 2; ++mi) {
        for (int nj = 0; nj < 2; ++nj) {
            int col = bn * 64 + wc + nj * 16 + lrow;
            float bsv = bias[col];
            for (int r = 0; r < 4; ++r) {
                int row = bm * 64 + wr + mi * 16 + rb + r;
                float v = acc[mi][nj][r] + bsv;
                v = v > 0.f ? v : 0.f;
                if (final_out) {
                    if (row < NREAL) final_out[(long)row * Nt + col] = v;
                } else {
                    hout[(long)row * HDIM + col] = f2bf(v);
                }
            }
        }
    }
}

static inline char* align256(char* p) {
    return (char*)(((size_t)p + 255) & ~(size_t)255);
}

extern "C" void kernel_launch(void* const* d_in, const int* in_sizes, int n_in,
                              void* d_out, int out_size, void* d_ws, size_t ws_size,
                              hipStream_t stream) {
    const float* x     = (const float*)d_in[0];
    const int*   eidx  = (const int*)  d_in[1];
    const float* attr  = (const float*)d_in[2];
    const float* wrel  = (const float*)d_in[3];
    const float* brel  = (const float*)d_in[4];
    const float* wroot = (const float*)d_in[5];
    const float* wout  = (const float*)d_in[6];
    const float* bout  = (const float*)d_in[7];
    const int* src = eidx;
    const int* dst = eidx + NEDGE;

    char* ws = (char*)d_ws;
    u16* hbfA  = (u16*)ws;        ws = align256(ws + (size_t)MPAD * HDIM * 2);
    u16* hbfB  = (u16*)ws;        ws = align256(ws + (size_t)MPAD * HDIM * 2);
    u16* aggbf = (u16*)ws;        ws = align256(ws + (size_t)MPAD * HDIM * 2);
    u16* brelT  = (u16*)ws;       ws = align256(ws + (size_t)3 * 65536 * 2);
    u16* brootT = (u16*)ws;       ws = align256(ws + (size_t)3 * 65536 * 2);
    u16* boutT  = (u16*)ws;       ws = align256(ws + (size_t)128 * 256 * 2);
    int* deg    = (int*)ws;       ws = align256(ws + (size_t)NREAL * 4);
    int* rowptr = (int*)ws;       ws = align256(ws + (size_t)(NREAL + 1) * 4);
    int* cursor = (int*)ws;       ws = align256(ws + (size_t)NREAL * 4);
    int* bsum   = (int*)ws;       ws = align256(ws + (size_t)SCAN_B * 4);
    int* boff   = (int*)ws;       ws = align256(ws + (size_t)SCAN_B * 4);
    u64* csr_edge = (u64*)ws;     ws = align256(ws + (size_t)NEDGE * 8);

    hipMemsetAsync(deg, 0, (size_t)NREAL * 4, stream);
    k_degree<<<(NEDGE + 255) / 256, 256, 0, stream>>>(dst, deg);
    k_blocksum<<<SCAN_B, 1024, 0, stream>>>(deg, bsum);
    k_scansmall<<<1, 64, 0, stream>>>(bsum, boff);
    k_scanfinal<<<SCAN_B, 1024, 0, stream>>>(deg, boff, rowptr, cursor);
    k_fill<<<(NEDGE + 255) / 256, 256, 0, stream>>>(src, dst, attr, cursor, csr_edge);
    k_sortseg<<<(NREAL + 3) / 4, 256, 0, stream>>>(rowptr, csr_edge);
    k_prep<<<PREP_B + 768, 256, 0, stream>>>(x, hbfA, wrel, wroot, wout, brelT, brootT, boutT);

    u16* h_c = hbfA;
    u16* h_n = hbfB;
    for (int l = 0; l < 3; ++l) {
        k_aggregate<<<MPAD / 4, 256, 0, stream>>>(h_c, rowptr, csr_edge, aggbf);
        k_gemm<<<dim3(313, 4), 256, 0, stream>>>(
            aggbf, h_c,
            brelT + (size_t)l * 65536, brootT + (size_t)l * 65536,
            brel + (size_t)l * HDIM,
            h_n, nullptr, HDIM);
        u16* tp = h_c; h_c = h_n; h_n = tp;
    }
    k_gemm<<<dim3(313, 2), 256, 0, stream>>>(
        h_c, nullptr, boutT, nullptr, bout,
        nullptr, (float*)d_out, ODIM);
}

// Round 6
// 218.245 us; speedup vs baseline: 1.5764x; 1.0827x over previous
//
#include <hip/hip_runtime.h>

#define NREAL 20000
#define MPAD  20096      // 157 * 128
#define HDIM  256
#define ODIM  128
#define NEDGE 320000
#define SCAN_B 20        // ceil(NREAL/1024)
#define PREP_B (MPAD * HDIM / 4 / 256)   // pad-convert blocks

typedef __attribute__((ext_vector_type(4))) float f32x4;
typedef __attribute__((ext_vector_type(8))) short s16x8;
typedef __attribute__((ext_vector_type(4))) unsigned short u16x4;
typedef unsigned short u16;
typedef unsigned long long u64;

__device__ inline u16 f2bf(float f) {
    unsigned int u = __float_as_uint(f);
    return (u16)((u + 0x7FFFu + ((u >> 16) & 1u)) >> 16);
}
__device__ inline float bf2f(u16 s) { return __uint_as_float(((unsigned)s) << 16); }

__device__ __forceinline__ void gload16(const void* g, void* l) {
    __builtin_amdgcn_global_load_lds((const __attribute__((address_space(1))) void*)g,
                                     (__attribute__((address_space(3))) void*)l, 16, 0, 0);
}

// ---------------- CSR build ----------------
__global__ void k_degree(const int* __restrict__ dst, int* __restrict__ deg) {
    int e = blockIdx.x * 256 + threadIdx.x;
    if (e < NEDGE) atomicAdd(&deg[dst[e]], 1);
}

__global__ __launch_bounds__(1024) void k_blocksum(const int* __restrict__ deg,
                                                   int* __restrict__ bsum) {
    __shared__ int red[16];
    int b = blockIdx.x, t = threadIdx.x;
    int i = b * 1024 + t;
    int v = (i < NREAL) ? deg[i] : 0;
    for (int off = 32; off; off >>= 1) v += __shfl_down(v, off);
    if ((t & 63) == 0) red[t >> 6] = v;
    __syncthreads();
    if (t < 16) {
        int s = red[t];
        for (int off = 8; off; off >>= 1) s += __shfl_down(s, off);
        if (t == 0) bsum[b] = s;
    }
}

__global__ void k_scansmall(const int* __restrict__ bsum, int* __restrict__ boff) {
    int t = threadIdx.x;  // one wave (64)
    int v = (t < SCAN_B) ? bsum[t] : 0;
    int orig = v;
    for (int off = 1; off < 64; off <<= 1) {
        int u = __shfl_up(v, off);
        if (t >= off) v += u;
    }
    if (t < SCAN_B) boff[t] = v - orig;
}

__global__ __launch_bounds__(1024) void k_scanfinal(const int* __restrict__ deg,
                                                    const int* __restrict__ boff,
                                                    int* __restrict__ rowptr,
                                                    int* __restrict__ cursor) {
    __shared__ int sm[1024];
    int b = blockIdx.x, t = threadIdx.x;
    int i = b * 1024 + t;
    int v = (i < NREAL) ? deg[i] : 0;
    sm[t] = v;
    __syncthreads();
    for (int off = 1; off < 1024; off <<= 1) {
        int u = (t >= off) ? sm[t - off] : 0;
        __syncthreads();
        if (t >= off) sm[t] += u;
        __syncthreads();
    }
    if (i < NREAL) {
        int excl = boff[b] + sm[t] - v;
        rowptr[i] = excl;
        cursor[i] = excl;
    }
    if (b == 0 && t == 0) rowptr[NREAL] = NEDGE;
}

__global__ void k_fill(const int* __restrict__ src, const int* __restrict__ dst,
                       const float* __restrict__ attr, int* __restrict__ cursor,
                       u64* __restrict__ csr_edge) {
    int e = blockIdx.x * 256 + threadIdx.x;
    if (e < NEDGE) {
        int d = dst[e];
        int p = atomicAdd(&cursor[d], 1);
        csr_edge[p] = ((u64)__float_as_uint(attr[e]) << 32) | (unsigned)src[e];
    }
}

// ---------------- canonical segment sort (determinism) ----------------
__global__ __launch_bounds__(256) void k_sortseg(const int* __restrict__ rowptr,
                                                 u64* __restrict__ csr_edge) {
    const int node = blockIdx.x * 4 + (threadIdx.x >> 6);
    const int lane = threadIdx.x & 63;
    if (node >= NREAL) return;
    const int beg = rowptr[node], end = rowptr[node + 1];
    const int m = end - beg;
    if (m <= 1) return;
    if (m <= 64) {
        u64 val = (lane < m) ? csr_edge[beg + lane] : ~0ull;
        #pragma unroll
        for (int ph = 0; ph < 64; ++ph) {
            int base = ph & 1;
            int partner = lane + (((lane ^ base) & 1) ? -1 : +1);
            if (partner < 0 || partner > 63) partner = lane;
            u64 p = __shfl(val, partner);
            if (partner != lane)
                val = (lane < partner) ? (val < p ? val : p) : (val > p ? val : p);
        }
        if (lane < m) csr_edge[beg + lane] = val;
    } else if (lane == 0) {
        for (int i = beg + 1; i < end; ++i) {
            u64 key = csr_edge[i];
            int j = i - 1;
            while (j >= beg && csr_edge[j] > key) { csr_edge[j + 1] = csr_edge[j]; --j; }
            csr_edge[j + 1] = key;
        }
    }
}

// ---------------- prep: pad-convert x to bf16 + weight transpose/convert ----------------
__global__ void k_prep(const float* __restrict__ x, u16* __restrict__ hbf,
                       const float* __restrict__ wrel, const float* __restrict__ wroot,
                       const float* __restrict__ wout,
                       u16* __restrict__ brelT, u16* __restrict__ brootT,
                       u16* __restrict__ boutT) {
    int b = blockIdx.x;
    if (b < PREP_B) {
        long gid  = (long)b * 256 + threadIdx.x;
        long base = gid * 4;
        long row  = base >> 8;
        f32x4 v = {0.f, 0.f, 0.f, 0.f};
        if (row < NREAL) v = *(const f32x4*)(x + base);
        u16x4 hv;
        for (int j = 0; j < 4; ++j) hv[j] = f2bf(v[j]);
        *(u16x4*)(hbf + base) = hv;
    } else {
        int i = (b - PREP_B) * 256 + threadIdx.x;
        if (i < 3 * 256 * 256) {
            int l = i >> 16, r = i & 65535, n = r >> 8, k = r & 255;
            brelT[i]  = f2bf(wrel [l * 65536 + k * 256 + n]);
            brootT[i] = f2bf(wroot[l * 65536 + k * 256 + n]);
        }
        if (i < 128 * 256) {
            int n = i >> 8, k = i & 255;
            boutT[i] = f2bf(wout[k * 128 + n]);
        }
    }
}

// ---------------- aggregation: wave per node, 2 edges/iter, bf16 gather ----------------
__global__ __launch_bounds__(256) void k_aggregate(
    const u16* __restrict__ hbf, const int* __restrict__ rowptr,
    const u64* __restrict__ csr_edge, u16* __restrict__ agg)
{
    const int node = blockIdx.x * 4 + (threadIdx.x >> 6);
    const int lane = threadIdx.x & 63;
    const int half = lane >> 5;
    const int col8 = (lane & 31) * 8;
    float acc[8] = {0.f,0.f,0.f,0.f,0.f,0.f,0.f,0.f};
    if (node < NREAL) {
        const int beg = rowptr[node], end = rowptr[node + 1];
        for (int c = beg; c < end; c += 64) {
            int m = end - c; if (m > 64) m = 64;
            u64 ej = csr_edge[c + (lane < m ? lane : 0)];
            int   sj = (int)(unsigned)ej;
            float aj = (lane < m) ? __uint_as_float((unsigned)(ej >> 32)) : 0.f;
            int npair = (m + 1) >> 1;
            #pragma unroll 4
            for (int p = 0; p < npair; ++p) {
                int sel = 2 * p + half;
                int   s = __shfl(sj, sel);
                float a = __shfl(aj, sel);
                s16x8 v = *(const s16x8*)(hbf + (long)s * HDIM + col8);
                #pragma unroll
                for (int q = 0; q < 8; ++q)
                    acc[q] += a * bf2f((u16)v[q]);
            }
        }
    }
    #pragma unroll
    for (int q = 0; q < 8; ++q)
        acc[q] += __shfl_xor(acc[q], 32);
    if (half == 0) {
        s16x8 hv;
        #pragma unroll
        for (int q = 0; q < 8; ++q) hv[q] = (short)f2bf(acc[q]);
        *(s16x8*)(agg + (long)node * HDIM + col8) = hv;
    }
}

// ---------------- GEMM: 128x128 tile, gload_lds staging, swizzled LDS ----------------
// A bf16 [MPAD][256]; B pre-transposed bf16 [Nt][256]. BK=32.
// LDS u16 index: swz(row,lk) = row*32 + (lk ^ (((row>>1)&3)<<3)); stage with
// pre-swizzled global source so gload_lds's linear write lands swizzled.
__global__ __launch_bounds__(256) void k_gemm(
    const u16* __restrict__ A1, const u16* __restrict__ A2,
    const u16* __restrict__ BT1, const u16* __restrict__ BT2,
    const float* __restrict__ bias,
    u16* __restrict__ hout, float* __restrict__ final_out, int Nt)
{
    __shared__ __align__(16) u16 As[128 * 32];
    __shared__ __align__(16) u16 Bs[128 * 32];

    const int t    = threadIdx.x;
    const int bm   = blockIdx.x, bn = blockIdx.y;
    const int lane = t & 63;
    const int wave = t >> 6;
    const int wr   = (wave >> 1) * 64;
    const int wc   = (wave & 1) * 64;
    const int lrow = lane & 15;
    const int lk   = (lane >> 4) * 8;

    f32x4 acc[4][4];
    #pragma unroll
    for (int i = 0; i < 4; ++i)
        #pragma unroll
        for (int j = 0; j < 4; ++j)
            #pragma unroll
            for (int r = 0; r < 4; ++r) acc[i][j][r] = 0.f;

    // staging geometry: chunk c = wave*2+i covers tile rows c*16..c*16+15,
    // lane covers row c*16 + (lane>>2), 16B slot (lane&3), source slot XOR-swizzled.
    const int crow0 = wave * 32 + (lane >> 2);   // +16*i
    const int slot  = lane & 3;

    const int nmat = A2 ? 2 : 1;
    for (int mat = 0; mat < nmat; ++mat) {
        const u16* A_g = mat ? A2  : A1;
        const u16* B_g = mat ? BT2 : BT1;
        #pragma unroll 2
        for (int k0 = 0; k0 < HDIM; k0 += 32) {
            __syncthreads();
            #pragma unroll
            for (int i = 0; i < 2; ++i) {
                int crow = crow0 + i * 16;
                int ss   = (slot ^ ((crow >> 1) & 3)) * 8;
                gload16(A_g + (size_t)(bm * 128 + crow) * HDIM + k0 + ss,
                        &As[(wave * 2 + i) * 512]);
                gload16(B_g + (size_t)(bn * 128 + crow) * HDIM + k0 + ss,
                        &Bs[(wave * 2 + i) * 512]);
            }
            __syncthreads();
            s16x8 bfr[4];
            #pragma unroll
            for (int nj = 0; nj < 4; ++nj) {
                int r = wc + nj * 16 + lrow;
                bfr[nj] = *(const s16x8*)&Bs[r * 32 + (lk ^ (((r >> 1) & 3) << 3))];
            }
            #pragma unroll
            for (int mi = 0; mi < 4; ++mi) {
                int r = wr + mi * 16 + lrow;
                s16x8 a = *(const s16x8*)&As[r * 32 + (lk ^ (((r >> 1) & 3) << 3))];
                #pragma unroll
                for (int nj = 0; nj < 4; ++nj)
                    acc[mi][nj] = __builtin_amdgcn_mfma_f32_16x16x32_bf16(a, bfr[nj], acc[mi][nj], 0, 0, 0);
            }
        }
    }

    // epilogue: bias + relu
    const int rb = (lane >> 4) * 4;
    #pragma unroll
    for (int mi = 0; mi < 4; ++mi) {
        #pragma unroll
        for (int nj = 0; nj < 4; ++nj) {
            int col = bn * 128 + wc + nj * 16 + lrow;
            float bsv = bias[col];
            #pragma unroll
            for (int r = 0; r < 4; ++r) {
                int row = bm * 128 + wr + mi * 16 + rb + r;
                float v = acc[mi][nj][r] + bsv;
                v = v > 0.f ? v : 0.f;
                if (final_out) {
                    if (row < NREAL) final_out[(long)row * Nt + col] = v;
                } else {
                    hout[(long)row * HDIM + col] = f2bf(v);
                }
            }
        }
    }
}

static inline char* align256(char* p) {
    return (char*)(((size_t)p + 255) & ~(size_t)255);
}

extern "C" void kernel_launch(void* const* d_in, const int* in_sizes, int n_in,
                              void* d_out, int out_size, void* d_ws, size_t ws_size,
                              hipStream_t stream) {
    const float* x     = (const float*)d_in[0];
    const int*   eidx  = (const int*)  d_in[1];
    const float* attr  = (const float*)d_in[2];
    const float* wrel  = (const float*)d_in[3];
    const float* brel  = (const float*)d_in[4];
    const float* wroot = (const float*)d_in[5];
    const float* wout  = (const float*)d_in[6];
    const float* bout  = (const float*)d_in[7];
    const int* src = eidx;
    const int* dst = eidx + NEDGE;

    char* ws = (char*)d_ws;
    u16* hbfA  = (u16*)ws;        ws = align256(ws + (size_t)MPAD * HDIM * 2);
    u16* hbfB  = (u16*)ws;        ws = align256(ws + (size_t)MPAD * HDIM * 2);
    u16* aggbf = (u16*)ws;        ws = align256(ws + (size_t)MPAD * HDIM * 2);
    u16* brelT  = (u16*)ws;       ws = align256(ws + (size_t)3 * 65536 * 2);
    u16* brootT = (u16*)ws;       ws = align256(ws + (size_t)3 * 65536 * 2);
    u16* boutT  = (u16*)ws;       ws = align256(ws + (size_t)128 * 256 * 2);
    int* deg    = (int*)ws;       ws = align256(ws + (size_t)NREAL * 4);
    int* rowptr = (int*)ws;       ws = align256(ws + (size_t)(NREAL + 1) * 4);
    int* cursor = (int*)ws;       ws = align256(ws + (size_t)NREAL * 4);
    int* bsum   = (int*)ws;       ws = align256(ws + (size_t)SCAN_B * 4);
    int* boff   = (int*)ws;       ws = align256(ws + (size_t)SCAN_B * 4);
    u64* csr_edge = (u64*)ws;     ws = align256(ws + (size_t)NEDGE * 8);

    hipMemsetAsync(deg, 0, (size_t)NREAL * 4, stream);
    k_degree<<<(NEDGE + 255) / 256, 256, 0, stream>>>(dst, deg);
    k_blocksum<<<SCAN_B, 1024, 0, stream>>>(deg, bsum);
    k_scansmall<<<1, 64, 0, stream>>>(bsum, boff);
    k_scanfinal<<<SCAN_B, 1024, 0, stream>>>(deg, boff, rowptr, cursor);
    k_fill<<<(NEDGE + 255) / 256, 256, 0, stream>>>(src, dst, attr, cursor, csr_edge);
    k_sortseg<<<(NREAL + 3) / 4, 256, 0, stream>>>(rowptr, csr_edge);
    k_prep<<<PREP_B + 768, 256, 0, stream>>>(x, hbfA, wrel, wroot, wout, brelT, brootT, boutT);

    u16* h_c = hbfA;
    u16* h_n = hbfB;
    for (int l = 0; l < 3; ++l) {
        k_aggregate<<<MPAD / 4, 256, 0, stream>>>(h_c, rowptr, csr_edge, aggbf);
        k_gemm<<<dim3(MPAD / 128, 2), 256, 0, stream>>>(
            aggbf, h_c,
            brelT + (size_t)l * 65536, brootT + (size_t)l * 65536,
            brel + (size_t)l * HDIM,
            h_n, nullptr, HDIM);
        u16* tp = h_c; h_c = h_n; h_n = tp;
    }
    k_gemm<<<dim3(MPAD / 128, 1), 256, 0, stream>>>(
        h_c, nullptr, boutT, nullptr, bout,
        nullptr, (float*)d_out, ODIM);
}